// Round 4
// baseline (87941.571 us; speedup 1.0000x reference)
//
#include <hip/hip_runtime.h>
#include <stdint.h>

#define Bz   64
#define Sz   512
#define Ez   512
#define Az   256
#define Dz   1024
#define Mz   128
#define Tz   800
#define G3   3072

#define SEG_STOP 6553600u
#define SEG_AW   6604800u

#define CB_BE   0
#define CB_BD   256
#define CB_V    512
#define CB_B1   768
#define CB_B2   1024
#define CB_BIH  1152
#define CB_BHH  4224
#define CB_BO   7296
#define CB_WS   7424
#define CB_BV   8960
#define CB_BS   8961
#define CB_N    8962

typedef __attribute__((ext_vector_type(8))) short short8;
typedef __attribute__((ext_vector_type(4))) float f32x4;
typedef unsigned short u16;

__device__ __forceinline__ f32x4 mfma16(short8 a, short8 b, f32x4 c) {
    return __builtin_amdgcn_mfma_f32_16x16x32_bf16(a, b, c, 0, 0, 0);
}
__device__ __forceinline__ float b2f(u16 u) { return __uint_as_float(((unsigned)u) << 16); }
__device__ __forceinline__ u16 f2b(float f) {
    unsigned x = __float_as_uint(f);
    return (u16)((x + 0x7fffu + ((x >> 16) & 1u)) >> 16);
}
__device__ __forceinline__ float ftanh(float x) { float e = __expf(2.f * x); return 1.f - 2.f / (e + 1.f); }
__device__ __forceinline__ float fsigm(float x) { return 1.f / (1.f + __expf(-x)); }

// input dtype detection: f32 data's even-index u16s are uniform mantissa bits
// (~18% plausible bf16 exponents); true bf16 data is ~100% plausible.
__global__ void detect_kernel(const u16* __restrict__ enc_u, int* __restrict__ dflag) {
    __shared__ int cnt_s;
    if (threadIdx.x == 0) cnt_s = 0;
    __syncthreads();
    int cnt = 0;
#pragma unroll
    for (int j = 0; j < 4; ++j) {
        u16 u = enc_u[2 * (threadIdx.x * 4 + j)];
        int e = (u >> 7) & 0xFF;
        cnt += (e >= 90 && e <= 135) ? 1 : 0;
    }
    atomicAdd(&cnt_s, cnt);
    __syncthreads();
    if (threadIdx.x == 0) *dflag = (cnt_s > 512) ? 1 : 0;
}

__global__ __launch_bounds__(256) void bias_kernel(
        const void* be, const void* bd, const void* v, const void* b1,
        const void* b2, const void* bih, const void* bhh, const void* bo,
        const void* Wsv, const void* bv, const void* bs,
        float* __restrict__ cb, const int* __restrict__ dflag) {
    const int i = blockIdx.x * 256 + threadIdx.x;
    if (i >= CB_N) return;
    const int flag = *dflag;
    const void* src; int rel;
    if      (i < CB_BD)  { src = be;  rel = i - CB_BE; }
    else if (i < CB_V)   { src = bd;  rel = i - CB_BD; }
    else if (i < CB_B1)  { src = v;   rel = i - CB_V; }
    else if (i < CB_B2)  { src = b1;  rel = i - CB_B1; }
    else if (i < CB_BIH) { src = b2;  rel = i - CB_B2; }
    else if (i < CB_BHH) { src = bih; rel = i - CB_BIH; }
    else if (i < CB_BO)  { src = bhh; rel = i - CB_BHH; }
    else if (i < CB_WS)  { src = bo;  rel = i - CB_BO; }
    else if (i < CB_BV)  { src = Wsv; rel = i - CB_WS; }
    else if (i < CB_BS)  { src = bv;  rel = i - CB_BV; }
    else                 { src = bs;  rel = i - CB_BS; }
    cb[i] = flag ? b2f(((const u16*)src)[rel]) : ((const float*)src)[rel];
}

__global__ __launch_bounds__(256) void conv_enc_kernel(const void* __restrict__ enc,
                                                       u16* __restrict__ enc16,
                                                       const int* __restrict__ dflag) {
    const int flag = *dflag;
    const size_t i8 = ((size_t)blockIdx.x * 256 + threadIdx.x) * 8;
    if (flag) {
        *(short8*)(enc16 + i8) = *(const short8*)((const u16*)enc + i8);
    } else {
        const float* f = (const float*)enc + i8;
        u16 tmp[8];
#pragma unroll
        for (int j = 0; j < 8; ++j) tmp[j] = f2b(f[j]);
        short8 s8; __builtin_memcpy(&s8, tmp, 16);
        *(short8*)(enc16 + i8) = s8;
    }
}

// pack W (K x N, row-major, f32 or bf16 per flag) into MFMA B-fragment tiles
__global__ __launch_bounds__(256) void pack_kernel(const void* __restrict__ W, u16* __restrict__ P,
                                                   int K, int N, const int* __restrict__ dflag) {
    const int flag = *dflag;
    int idx = blockIdx.x * 256 + threadIdx.x;
    int kt = K >> 5;
    int ntiles = (N >> 4) * kt;
    if (idx >= ntiles * 64) return;
    int tile = idx >> 6, lane = idx & 63;
    int n0 = (tile / kt) << 4;
    int kk = (tile % kt) << 5;
    int col = n0 + (lane & 15);
    int krow = kk + ((lane >> 4) << 3);
    u16 tmp[8];
    if (flag) {
        const u16* Wu = (const u16*)W;
#pragma unroll
        for (int j = 0; j < 8; ++j) tmp[j] = Wu[(size_t)(krow + j) * N + col];
    } else {
        const float* Wf = (const float*)W;
#pragma unroll
        for (int j = 0; j < 8; ++j) tmp[j] = f2b(Wf[(size_t)(krow + j) * N + col]);
    }
    short8 s8;
    __builtin_memcpy(&s8, tmp, 16);
    *(short8*)(P + (size_t)tile * 512 + lane * 8) = s8;
}

__global__ __launch_bounds__(256) void prenet_kernel(const void* __restrict__ tm,
                                                     const u16* __restrict__ W1P,
                                                     const u16* __restrict__ W2P,
                                                     const float* __restrict__ cb,
                                                     u16* __restrict__ pre_all,
                                                     const int* __restrict__ dflag) {
    __shared__ u16 p1s[64 * 264];
    const int flag = *dflag;
    const int t = blockIdx.x;
    const int tid = threadIdx.x, lane = tid & 63, w = tid >> 6;
    const int row = w * 16 + (lane & 15);
    const int koff = (lane >> 4) * 8;
    short8 zero8 = {0, 0, 0, 0, 0, 0, 0, 0};
    f32x4 acc[16];
#pragma unroll
    for (int n = 0; n < 16; ++n) acc[n] = (f32x4){0.f, 0.f, 0.f, 0.f};
#pragma unroll
    for (int ks = 0; ks < 4; ++ks) {
        short8 a = zero8;
        if (t > 0) {
            const size_t idx = (size_t)row * (Tz * Mz) + (size_t)(t - 1) * Mz + ks * 32 + koff;
            if (flag) {
                a = *(const short8*)((const u16*)tm + idx);
            } else {
                const float* tf = (const float*)tm + idx;
                u16 tmp[8];
#pragma unroll
                for (int j = 0; j < 8; ++j) tmp[j] = f2b(tf[j]);
                __builtin_memcpy(&a, tmp, 16);
            }
        }
#pragma unroll
        for (int n = 0; n < 16; ++n) {
            short8 b = *(const short8*)(W1P + (size_t)(n * 4 + ks) * 512 + lane * 8);
            acc[n] = mfma16(a, b, acc[n]);
        }
    }
#pragma unroll
    for (int n = 0; n < 16; ++n) {
        int col = n * 16 + (lane & 15);
        float bb = cb[CB_B1 + col];
#pragma unroll
        for (int r = 0; r < 4; ++r) {
            int rr = w * 16 + (lane >> 4) * 4 + r;
            float vf = acc[n][r] + bb;
            p1s[rr * 264 + col] = f2b(vf > 0.f ? vf : 0.f);
        }
    }
    __syncthreads();
    f32x4 acc2[8];
#pragma unroll
    for (int n = 0; n < 8; ++n) acc2[n] = (f32x4){0.f, 0.f, 0.f, 0.f};
#pragma unroll
    for (int ks = 0; ks < 8; ++ks) {
        short8 a = *(const short8*)(p1s + row * 264 + ks * 32 + koff);
#pragma unroll
        for (int n = 0; n < 8; ++n) {
            short8 b = *(const short8*)(W2P + (size_t)(n * 8 + ks) * 512 + lane * 8);
            acc2[n] = mfma16(a, b, acc2[n]);
        }
    }
#pragma unroll
    for (int n = 0; n < 8; ++n) {
        int col = n * 16 + (lane & 15);
        float bb = cb[CB_B2 + col];
#pragma unroll
        for (int r = 0; r < 4; ++r) {
            int rr = w * 16 + (lane >> 4) * 4 + r;
            float vf = acc2[n][r] + bb;
            pre_all[((size_t)t * 64 + rr) * 128 + col] = f2b(vf > 0.f ? vf : 0.f);
        }
    }
}

__global__ __launch_bounds__(256) void encproj_kernel(const u16* __restrict__ enc16,
                                                      const u16* __restrict__ WeP,
                                                      const float* __restrict__ cb,
                                                      u16* __restrict__ ep) {
    const int tid = threadIdx.x, lane = tid & 63, w = tid >> 6;
    const int mb = blockIdx.x >> 2, nb = blockIdx.x & 3;
    const int m0 = mb * 64 + w * 16;
    const int row = m0 + (lane & 15);
    const int koff = (lane >> 4) * 8;
    f32x4 acc[4];
#pragma unroll
    for (int n = 0; n < 4; ++n) acc[n] = (f32x4){0.f, 0.f, 0.f, 0.f};
#pragma unroll 4
    for (int ks = 0; ks < 16; ++ks) {
        short8 a = *(const short8*)(enc16 + (size_t)row * Ez + ks * 32 + koff);
#pragma unroll
        for (int n = 0; n < 4; ++n) {
            short8 b = *(const short8*)(WeP + (size_t)((nb * 4 + n) * 16 + ks) * 512 + lane * 8);
            acc[n] = mfma16(a, b, acc[n]);
        }
    }
#pragma unroll
    for (int n = 0; n < 4; ++n) {
        int col = nb * 64 + n * 16 + (lane & 15);
        float bb = cb[CB_BE + col];
#pragma unroll
        for (int r = 0; r < 4; ++r) {
            int rr = m0 + (lane >> 4) * 4 + r;
            ep[(size_t)rr * Az + col] = f2b(acc[n][r] + bb);
        }
    }
}

__global__ void init_kernel(float* hf, u16* hhi, u16* hlo) {
    int i = blockIdx.x * 256 + threadIdx.x;
    if (i < Bz * Dz) { hf[i] = 0.f; hhi[i] = 0; hlo[i] = 0; }
}

__global__ void sentinel_kernel(void* out, int out_size) {
    ((float*)out)[0] = 12345.f;
    ((u16*)out)[out_size - 1] = f2b(12345.f);
}

struct DecP {
    const u16 *enc16, *ep, *pre;
    const u16 *WhhP, *WihP, *WdP, *WoP;
    const float* cb;
    float *gh, *dp, *ctxP, *ews, *psumP, *hf;
    u16 *ctxn, *hhi, *hlo;
    void *dout;
    const int* dflag;
};

__device__ __forceinline__ void out_write(void* base, size_t elem, float v, int flag) {
    if (flag) ((u16*)base)[elem] = f2b(v);
    else      ((float*)base)[elem] = v;
}

__device__ __forceinline__ void mel_part(const DecP& p, int mblk, int lane, int w, int tt, int flag) {
    const int m = w >> 1, nh = w & 1;
    const int row = m * 16 + (lane & 15);
    const int koff = (lane >> 4) * 8;
    const size_t tb = (size_t)(mblk * 2 + nh) * 48;
    f32x4 acc = {0.f, 0.f, 0.f, 0.f};
#pragma unroll 4
    for (int ks = 0; ks < 48; ++ks) {
        const int k = ks * 32 + koff;
        short8 a;
        if (ks < 32) a = *(const short8*)(p.hhi + (size_t)row * Dz + k);
        else         a = *(const short8*)(p.ctxn + (size_t)row * Ez + (k - Dz));
        short8 b = *(const short8*)(p.WoP + (tb + ks) * 512 + lane * 8);
        acc = mfma16(a, b, acc);
    }
    const int col = mblk * 32 + nh * 16 + (lane & 15);
    const float bb = p.cb[CB_BO + col];
#pragma unroll
    for (int r = 0; r < 4; ++r) {
        int rr = m * 16 + (lane >> 4) * 4 + r;
        out_write(p.dout, (size_t)rr * (Tz * Mz) + (size_t)(tt - 1) * Mz + col, acc[r] + bb, flag);
    }
}

__device__ __forceinline__ void stop_part(const DecP& p, int tid, int tt, int flag) {
    const int rr = tid >> 3, kq = tid & 7;
    const int k0 = kq * 192;
    float acc = 0.f;
#pragma unroll 4
    for (int k = k0; k < k0 + 192; ++k) {
        float x = (k < Dz) ? p.hf[(size_t)rr * Dz + k] : b2f(p.ctxn[(size_t)rr * Ez + (k - Dz)]);
        acc += x * p.cb[CB_WS + k];
    }
    acc += __shfl_xor(acc, 1);
    acc += __shfl_xor(acc, 2);
    acc += __shfl_xor(acc, 4);
    if (kq == 0) out_write(p.dout, SEG_STOP + (size_t)rr * Tz + (tt - 1), acc + p.cb[CB_BS], flag);
}

__global__ __launch_bounds__(512) void step1_kernel(DecP p, int t) {
    const int tid = threadIdx.x, blk = blockIdx.x;
    const int lane = tid & 63, w = tid >> 6;
    if (blk < 96) {
        const int m = w >> 1, nh = w & 1;
        const int row = m * 16 + (lane & 15);
        const int koff = (lane >> 4) * 8;
        const size_t tb = (size_t)(blk * 2 + nh) * 32;
        const u16* ph = p.hhi + (size_t)row * Dz + koff;
        const u16* pl = p.hlo + (size_t)row * Dz + koff;
        const u16* pb = p.WhhP + tb * 512 + lane * 8;
        f32x4 acc = {0.f, 0.f, 0.f, 0.f};
#pragma unroll 8
        for (int ks = 0; ks < 32; ++ks) {
            short8 b = *(const short8*)(pb + (size_t)ks * 512);
            short8 ah = *(const short8*)(ph + ks * 32);
            short8 al = *(const short8*)(pl + ks * 32);
            acc = mfma16(ah, b, acc);
            acc = mfma16(al, b, acc);
        }
        const int col = blk * 32 + nh * 16 + (lane & 15);
        const float bb = p.cb[CB_BHH + col];
#pragma unroll
        for (int r = 0; r < 4; ++r) {
            int rr = m * 16 + (lane >> 4) * 4 + r;
            p.gh[(size_t)rr * G3 + col] = acc[r] + bb;
        }
    } else if (blk < 104) {
        const int m = w >> 1, nh = w & 1;
        const int row = m * 16 + (lane & 15);
        const int koff = (lane >> 4) * 8;
        const size_t tb = (size_t)((blk - 96) * 2 + nh) * 32;
        const u16* ph = p.hhi + (size_t)row * Dz + koff;
        const u16* pb = p.WdP + tb * 512 + lane * 8;
        f32x4 acc = {0.f, 0.f, 0.f, 0.f};
#pragma unroll 8
        for (int ks = 0; ks < 32; ++ks) {
            short8 b = *(const short8*)(pb + (size_t)ks * 512);
            short8 a = *(const short8*)(ph + ks * 32);
            acc = mfma16(a, b, acc);
        }
        const int col = (blk - 96) * 32 + nh * 16 + (lane & 15);
        const float bb = p.cb[CB_BD + col];
#pragma unroll
        for (int r = 0; r < 4; ++r) {
            int rr = m * 16 + (lane >> 4) * 4 + r;
            p.dp[(size_t)rr * Az + col] = acc[r] + bb;
        }
    } else if (blk < 108) {
        if (t > 0) mel_part(p, blk - 104, lane, w, t, *p.dflag);
    } else {
        if (t > 0) stop_part(p, tid, t, *p.dflag);
    }
}

__global__ __launch_bounds__(512) void step2_kernel(DecP p, int t) {
    __shared__ __align__(16) float smem[256 + 256 + 128 + 8];
    const int tid = threadIdx.x, blk = blockIdx.x;
    const int lane = tid & 63, w = tid >> 6;
    const float bvf = p.cb[CB_BV];
    float* dp_l = smem;
    float* v_l = dp_l + 256;
    float* e_l = v_l + 256;
    float* red = e_l + 128;
    const int b = blk >> 2, chunk = blk & 3, s0 = chunk * 128;
    if (tid < 256) { dp_l[tid] = p.dp[b * Az + tid]; v_l[tid] = p.cb[CB_V + tid]; }
    __syncthreads();
    const int sl = tid >> 2, q = tid & 3, a0 = q * 64;
    float sc = 0.f;
    const u16* prow = p.ep + ((size_t)(b * Sz + s0 + sl)) * Az + a0;
#pragma unroll
    for (int it = 0; it < 8; ++it) {
        short8 ev = *(const short8*)(prow + it * 8);
#pragma unroll
        for (int j = 0; j < 8; ++j) {
            int a = a0 + it * 8 + j;
            sc += v_l[a] * ftanh(b2f((u16)ev[j]) + dp_l[a]);
        }
    }
    sc += __shfl_xor(sc, 1);
    sc += __shfl_xor(sc, 2);
    float e = 0.f;
    if (q == 0) {
        e = __expf(fminf(sc + bvf, 30.f));
        e_l[sl] = e;
        p.ews[b * Sz + s0 + sl] = e;
    }
    float pe = e;
#pragma unroll
    for (int off = 1; off < 64; off <<= 1) pe += __shfl_xor(pe, off);
    if (lane == 0) red[w] = pe;
    __syncthreads();
    if (tid == 0) {
        float s = 0.f;
#pragma unroll
        for (int i = 0; i < 8; ++i) s += red[i];
        p.psumP[b * 4 + chunk] = s;
    }
    float cacc = 0.f;
    const u16* eb = p.enc16 + ((size_t)(b * Sz + s0)) * Ez + tid;
#pragma unroll 4
    for (int s = 0; s < 128; ++s) cacc += e_l[s] * b2f(eb[(size_t)s * Ez]);
    p.ctxP[((size_t)b * 4 + chunk) * Ez + tid] = cacc;
}

__global__ __launch_bounds__(512) void step3_kernel(DecP p, int t) {
    __shared__ __align__(16) char smem[64 * 136 * 2 + 512];
    const int tid = threadIdx.x, blk = blockIdx.x;
    const int lane = tid & 63, w = tid >> 6;
    if (blk < 32) {
        u16* x_l = (u16*)smem;
        float* ps_l = (float*)(smem + 64 * 136 * 2);
        if (tid < 64) {
            const float* pp = p.psumP + tid * 4;
            float ps = pp[0] + pp[1] + pp[2] + pp[3];
            ps_l[tid] = 1.f / fmaxf(ps, 1e-20f);
        }
        const int m = w >> 1, nh = w & 1;
        const int d0 = blk * 32;
        const size_t tbR = (size_t)(blk * 2 + nh) * 20;
        const size_t tbZ = (size_t)(64 + blk * 2 + nh) * 20;
        const size_t tbN = (size_t)(128 + blk * 2 + nh) * 20;
        const int row = m * 16 + (lane & 15);
        const int koff = (lane >> 4) * 8;
        f32x4 aR = {0.f, 0.f, 0.f, 0.f}, aZ = {0.f, 0.f, 0.f, 0.f}, aN = {0.f, 0.f, 0.f, 0.f};
        for (int c = 0; c < 5; ++c) {
            __syncthreads();
            const int rr = tid >> 3, kb = (tid & 7) * 16;
            if (c == 0) {
                const u16* src = p.pre + ((size_t)t * 64 + rr) * 128 + kb;
                *(short8*)(x_l + rr * 136 + kb) = *(const short8*)src;
                *(short8*)(x_l + rr * 136 + kb + 8) = *(const short8*)(src + 8);
            } else {
                const float inv = ps_l[rr];
                const float* s0p = p.ctxP + ((size_t)rr * 4 + 0) * Ez + (c - 1) * 128 + kb;
                const float* s1p = s0p + Ez;
                const float* s2p = s0p + 2 * Ez;
                const float* s3p = s0p + 3 * Ez;
                u16 tmp[16];
#pragma unroll
                for (int j = 0; j < 16; ++j)
                    tmp[j] = f2b((s0p[j] + s1p[j] + s2p[j] + s3p[j]) * inv);
                short8 s0v, s1v;
                __builtin_memcpy(&s0v, tmp, 16);
                __builtin_memcpy(&s1v, tmp + 8, 16);
                *(short8*)(x_l + rr * 136 + kb) = s0v;
                *(short8*)(x_l + rr * 136 + kb + 8) = s1v;
            }
            __syncthreads();
#pragma unroll
            for (int ksl = 0; ksl < 4; ++ksl) {
                short8 a = *(const short8*)(x_l + row * 136 + ksl * 32 + koff);
                const int ks = c * 4 + ksl;
                short8 bR = *(const short8*)(p.WihP + (tbR + ks) * 512 + lane * 8);
                short8 bZ = *(const short8*)(p.WihP + (tbZ + ks) * 512 + lane * 8);
                short8 bN = *(const short8*)(p.WihP + (tbN + ks) * 512 + lane * 8);
                aR = mfma16(a, bR, aR);
                aZ = mfma16(a, bZ, aZ);
                aN = mfma16(a, bN, aN);
            }
        }
        const int col = d0 + nh * 16 + (lane & 15);
        const float biR = p.cb[CB_BIH + col];
        const float biZ = p.cb[CB_BIH + Dz + col];
        const float biN = p.cb[CB_BIH + 2 * Dz + col];
#pragma unroll
        for (int r = 0; r < 4; ++r) {
            int rr = m * 16 + (lane >> 4) * 4 + r;
            float gR = p.gh[(size_t)rr * G3 + col];
            float gZ = p.gh[(size_t)rr * G3 + Dz + col];
            float gN = p.gh[(size_t)rr * G3 + 2 * Dz + col];
            float rg = fsigm(aR[r] + biR + gR);
            float zg = fsigm(aZ[r] + biZ + gZ);
            float ng = ftanh(aN[r] + biN + rg * gN);
            float hp = p.hf[(size_t)rr * Dz + col];
            float hn = (1.f - zg) * ng + zg * hp;
            p.hf[(size_t)rr * Dz + col] = hn;
            u16 hb = f2b(hn);
            p.hhi[(size_t)rr * Dz + col] = hb;
            p.hlo[(size_t)rr * Dz + col] = f2b(hn - b2f(hb));
        }
    } else {
        const int flag = *p.dflag;
        const int bg = (blk - 32) * 4;
#pragma unroll
        for (int bi = 0; bi < 4; ++bi) {
            const int b = bg + bi;
            const float* pp = p.psumP + b * 4;
            const float inv = 1.f / fmaxf(pp[0] + pp[1] + pp[2] + pp[3], 1e-20f);
            float e = p.ews[b * Sz + tid];
            out_write(p.dout, SEG_AW + (size_t)b * (Tz * Sz) + (size_t)t * Sz + tid, e * inv, flag);
            float cu = p.ctxP[((size_t)b * 4 + 0) * Ez + tid]
                     + p.ctxP[((size_t)b * 4 + 1) * Ez + tid]
                     + p.ctxP[((size_t)b * 4 + 2) * Ez + tid]
                     + p.ctxP[((size_t)b * 4 + 3) * Ez + tid];
            p.ctxn[b * Ez + tid] = f2b(cu * inv);
        }
    }
}

__global__ __launch_bounds__(512) void fin_kernel(DecP p) {
    const int tid = threadIdx.x, blk = blockIdx.x;
    const int lane = tid & 63, w = tid >> 6;
    const int flag = *p.dflag;
    if (blk < 4) mel_part(p, blk, lane, w, Tz, flag);
    else stop_part(p, tid, Tz, flag);
}

extern "C" void kernel_launch(void* const* d_in, const int* in_sizes, int n_in,
                              void* d_out, int out_size, void* d_ws, size_t ws_size,
                              hipStream_t stream) {
    (void)in_sizes; (void)n_in;
    const void* enc = d_in[0];
    const void* tm  = d_in[1];
    const void* We  = d_in[2];
    const void* be  = d_in[3];
    const void* Wd  = d_in[4];
    const void* bd  = d_in[5];
    const void* v   = d_in[6];
    const void* bv  = d_in[7];
    const void* W1  = d_in[8];
    const void* b1  = d_in[9];
    const void* W2  = d_in[10];
    const void* b2  = d_in[11];
    const void* Wih = d_in[12];
    const void* bih = d_in[13];
    const void* Whh = d_in[14];
    const void* bhh = d_in[15];
    const void* Wo  = d_in[16];
    const void* bo  = d_in[17];
    const void* Wsv = d_in[18];
    const void* bs  = d_in[19];

    const size_t WS_NEED = 77107212;
    if (ws_size < WS_NEED) {
        sentinel_kernel<<<1, 1, 0, stream>>>(d_out, out_size);
        return;
    }

    char* ws = (char*)d_ws;
    u16*   WhhP = (u16*)(ws + 0);
    u16*   WihP = (u16*)(ws + 6291456);
    u16*   WdP  = (u16*)(ws + 10223616);
    u16*   WoP  = (u16*)(ws + 10747904);
    u16*   WeP  = (u16*)(ws + 11141120);
    u16*   W1P  = (u16*)(ws + 11403264);
    u16*   W2P  = (u16*)(ws + 11468800);
    u16*   ep   = (u16*)(ws + 11534336);
    u16*   pre  = (u16*)(ws + 28311552);
    float* gh   = (float*)(ws + 41418752);
    float* dp   = (float*)(ws + 42205184);
    float* ctxP = (float*)(ws + 42270720);
    float* ews  = (float*)(ws + 42795008);
    u16*   ctxn = (u16*)(ws + 42926080);
    float* hf   = (float*)(ws + 42991616);
    u16*   hhi  = (u16*)(ws + 43253760);
    u16*   hlo  = (u16*)(ws + 43384832);
    float* psumP = (float*)(ws + 43515904);
    u16*   enc16 = (u16*)(ws + 43516928);
    float* cb    = (float*)(ws + 77071360);
    int*   dflag = (int*)(ws + 77107208);

    detect_kernel<<<1, 256, 0, stream>>>((const u16*)enc, dflag);
    bias_kernel<<<36, 256, 0, stream>>>(be, bd, v, b1, b2, bih, bhh, bo, Wsv, bv, bs, cb, dflag);
    conv_enc_kernel<<<8192, 256, 0, stream>>>(enc, enc16, dflag);
    pack_kernel<<<1536, 256, 0, stream>>>(Whh, WhhP, 1024, 3072, dflag);
    pack_kernel<<<960,  256, 0, stream>>>(Wih, WihP, 640, 3072, dflag);
    pack_kernel<<<128,  256, 0, stream>>>(Wd,  WdP,  1024, 256, dflag);
    pack_kernel<<<96,   256, 0, stream>>>(Wo,  WoP,  1536, 128, dflag);
    pack_kernel<<<64,   256, 0, stream>>>(We,  WeP,  512, 256, dflag);
    pack_kernel<<<16,   256, 0, stream>>>(W1,  W1P,  128, 256, dflag);
    pack_kernel<<<16,   256, 0, stream>>>(W2,  W2P,  256, 128, dflag);
    prenet_kernel<<<800, 256, 0, stream>>>(tm, W1P, W2P, cb, pre, dflag);
    encproj_kernel<<<2048, 256, 0, stream>>>(enc16, WeP, cb, ep);
    init_kernel<<<256, 256, 0, stream>>>(hf, hhi, hlo);

    DecP P;
    P.enc16 = enc16; P.ep = ep; P.pre = pre;
    P.WhhP = WhhP; P.WihP = WihP; P.WdP = WdP; P.WoP = WoP;
    P.cb = cb;
    P.gh = gh; P.dp = dp; P.ctxP = ctxP; P.ews = ews; P.psumP = psumP; P.hf = hf;
    P.ctxn = ctxn; P.hhi = hhi; P.hlo = hlo;
    P.dout = d_out;
    P.dflag = dflag;

    for (int t = 0; t < Tz; ++t) {
        step1_kernel<<<109, 512, 0, stream>>>(P, t);
        step2_kernel<<<256, 512, 0, stream>>>(P, t);
        step3_kernel<<<48,  512, 0, stream>>>(P, t);
    }
    fin_kernel<<<5, 512, 0, stream>>>(P);
}